// Round 1
// baseline (656.862 us; speedup 1.0000x reference)
//
#include <hip/hip_runtime.h>
#include <math.h>

#define N_NODES 50000
#define N_EDGES 1000000
#define N_HID 64
#define N_GRAPHS 500
#define IN_DIM 4

// ---------------- degree / norm ----------------
__global__ void k_init_deg(float* deg) {
    int i = blockIdx.x * blockDim.x + threadIdx.x;
    if (i < N_NODES) deg[i] = 1.0f;  // self-loop
}

__global__ void k_deg_scatter(const int* __restrict__ ei, float* deg) {
    int e = blockIdx.x * blockDim.x + threadIdx.x;
    if (e < N_EDGES) atomicAdd(&deg[ei[N_EDGES + e]], 1.0f);
}

__global__ void k_dis(float* deg) {
    int i = blockIdx.x * blockDim.x + threadIdx.x;
    if (i < N_NODES) deg[i] = 1.0f / sqrtf(deg[i]);  // deg >= 1 always
}

// ---------------- h = x @ W1  (x: [N,4], W1: [4,64]) ----------------
__global__ void k_gemm_in(const float* __restrict__ x, const float* __restrict__ W1,
                          float* __restrict__ h) {
    __shared__ float sW[IN_DIM * N_HID];
    int t = threadIdx.x;
    for (int i = t; i < IN_DIM * N_HID; i += blockDim.x) sW[i] = W1[i];
    __syncthreads();
    int node = blockIdx.x * (blockDim.x / N_HID) + t / N_HID;
    int j = t % N_HID;
    if (node < N_NODES) {
        float acc = 0.f;
#pragma unroll
        for (int k = 0; k < IN_DIM; ++k) acc += x[node * IN_DIM + k] * sW[k * N_HID + j];
        h[node * N_HID + j] = acc;
    }
}

// ---------------- agg init with self-loop contribution ----------------
__global__ void k_selfloop(const float* __restrict__ h, const float* __restrict__ dis,
                           float* __restrict__ agg) {
    int idx = blockIdx.x * blockDim.x + threadIdx.x;
    if (idx < N_NODES * N_HID) {
        int node = idx >> 6;
        float d = dis[node];
        agg[idx] = h[idx] * d * d;
    }
}

// ---------------- edge gather+scatter: one wave per edge ----------------
__global__ void k_edge_scatter(const int* __restrict__ ei, const float* __restrict__ h,
                               const float* __restrict__ dis, float* agg) {
    long long t = (long long)blockIdx.x * blockDim.x + threadIdx.x;
    int e = (int)(t >> 6);
    int j = (int)(t & 63);
    if (e < N_EDGES) {
        int s = ei[e];
        int d = ei[N_EDGES + e];
        float w = dis[s] * dis[d];
        atomicAdd(&agg[d * N_HID + j], h[s * N_HID + j] * w);
    }
}

// ---------------- out = elu(out + b) in place ----------------
__global__ void k_bias_elu(float* buf, const float* __restrict__ b) {
    int idx = blockIdx.x * blockDim.x + threadIdx.x;
    if (idx < N_NODES * N_HID) {
        float v = buf[idx] + b[idx & 63];
        buf[idx] = v > 0.f ? v : expm1f(v);
    }
}

// ---------------- out = act @ W2  (per node 64-dot) ----------------
#define NPB 4  // nodes per 256-thread block
__global__ void k_gemm_hid(const float* __restrict__ act, const float* __restrict__ W2,
                           float* __restrict__ out) {
    __shared__ float sW[N_HID * N_HID];
    __shared__ float sA[NPB][N_HID];
    int t = threadIdx.x;  // 256
    for (int i = t; i < N_HID * N_HID; i += 256) sW[i] = W2[i];
    int nl = t / N_HID, j = t % N_HID;
    int node = blockIdx.x * NPB + nl;
    if (node < N_NODES) sA[nl][j] = act[node * N_HID + j];
    __syncthreads();
    if (node < N_NODES) {
        float acc = 0.f;
#pragma unroll
        for (int k = 0; k < N_HID; ++k) acc += sA[nl][k] * sW[k * N_HID + j];
        out[node * N_HID + j] = acc;
    }
}

// ---------------- pooling ----------------
__global__ void k_pool_init(float* sums, float* cnts) {
    int i = blockIdx.x * blockDim.x + threadIdx.x;
    if (i < N_GRAPHS * N_HID) sums[i] = 0.f;
    if (i < N_GRAPHS) cnts[i] = 0.f;
}

__global__ void k_pool(const float* __restrict__ h, const int* __restrict__ batch,
                       float* sums, float* cnts) {
    int idx = blockIdx.x * blockDim.x + threadIdx.x;
    if (idx < N_NODES * N_HID) {
        int node = idx >> 6, j = idx & 63;
        int g = batch[node];
        atomicAdd(&sums[g * N_HID + j], h[idx]);
        if (j == 0) atomicAdd(&cnts[g], 1.0f);
    }
}

// ---------------- final: out[g] = dot(pooled[g], W3) + b3 ----------------
__global__ void k_final(const float* __restrict__ sums, const float* __restrict__ cnts,
                        const float* __restrict__ W3, const float* __restrict__ b3,
                        float* out) {
    int g = blockIdx.x;
    int j = threadIdx.x;  // 64 = one wave
    float v = sums[g * N_HID + j] / fmaxf(cnts[g], 1.0f);
    float p = v * W3[j];
#pragma unroll
    for (int off = 32; off; off >>= 1) p += __shfl_down(p, off);
    if (j == 0) out[g] = p + b3[0];
}

extern "C" void kernel_launch(void* const* d_in, const int* in_sizes, int n_in,
                              void* d_out, int out_size, void* d_ws, size_t ws_size,
                              hipStream_t stream) {
    const float* x   = (const float*)d_in[0];
    const int*   ei  = (const int*)d_in[1];   // [2, E] row-major: row0=src, row1=dst
    const int*   bat = (const int*)d_in[2];
    const float* W1  = (const float*)d_in[3];
    const float* b1  = (const float*)d_in[4];
    const float* W2  = (const float*)d_in[5];
    const float* b2  = (const float*)d_in[6];
    const float* W3  = (const float*)d_in[7];
    const float* b3  = (const float*)d_in[8];
    float* out = (float*)d_out;

    // workspace carve-up (floats)
    float* ws   = (float*)d_ws;
    float* deg  = ws;                       // 50048 (dis after k_dis, in place)
    float* bufA = deg + 50048;              // 3.2M
    float* bufB = bufA + (size_t)N_NODES * N_HID;  // 3.2M
    float* sums = bufB + (size_t)N_NODES * N_HID;  // 32000
    float* cnts = sums + (size_t)N_GRAPHS * N_HID; // 500

    const int B = 256;
    const int gN   = (N_NODES + B - 1) / B;
    const int gE   = (N_EDGES + B - 1) / B;
    const int gNH  = (N_NODES * N_HID + B - 1) / B;
    const int gEW  = (int)(((long long)N_EDGES * 64 + B - 1) / B);

    // degrees -> dis (shared by both conv layers)
    k_init_deg<<<gN, B, 0, stream>>>(deg);
    k_deg_scatter<<<gE, B, 0, stream>>>(ei, deg);
    k_dis<<<gN, B, 0, stream>>>(deg);

    // layer 1
    k_gemm_in<<<(N_NODES + NPB - 1) / NPB, B, 0, stream>>>(x, W1, bufA);
    k_selfloop<<<gNH, B, 0, stream>>>(bufA, deg, bufB);
    k_edge_scatter<<<gEW, B, 0, stream>>>(ei, bufA, deg, bufB);
    k_bias_elu<<<gNH, B, 0, stream>>>(bufB, b1);

    // layer 2
    k_gemm_hid<<<(N_NODES + NPB - 1) / NPB, B, 0, stream>>>(bufB, W2, bufA);
    k_selfloop<<<gNH, B, 0, stream>>>(bufA, deg, bufB);
    k_edge_scatter<<<gEW, B, 0, stream>>>(ei, bufA, deg, bufB);
    k_bias_elu<<<gNH, B, 0, stream>>>(bufB, b2);

    // pooling + head
    k_pool_init<<<(N_GRAPHS * N_HID + B - 1) / B, B, 0, stream>>>(sums, cnts);
    k_pool<<<gNH, B, 0, stream>>>(bufB, bat, sums, cnts);
    k_final<<<N_GRAPHS, N_HID, 0, stream>>>(sums, cnts, W3, b3, out);
}

// Round 2
// 371.983 us; speedup vs baseline: 1.7658x; 1.7658x over previous
//
#include <hip/hip_runtime.h>
#include <math.h>

#define N_NODES 50000
#define N_EDGES 1000000
#define N_HID 64
#define N_GRAPHS 500
#define IN_DIM 4
#define NPAD 50048           // N_NODES rounded to 256
#define NB_SCAN 196          // ceil(50000/256)

// ---------- CSR build: histogram of in-degrees ----------
__global__ void k_hist(const int* __restrict__ ei, int* cnt) {
    int e = blockIdx.x * blockDim.x + threadIdx.x;
    if (e < N_EDGES) atomicAdd(&cnt[ei[N_EDGES + e]], 1);
}

// ---------- scan step 1: per-256-block exclusive scan + block sums ----------
__global__ void k_scan1(const int* __restrict__ cnt, int* offs, int* bsum) {
    __shared__ int s[256];
    int tid = threadIdx.x;
    int i = blockIdx.x * 256 + tid;
    int v = (i < N_NODES) ? cnt[i] : 0;
    s[tid] = v;
    __syncthreads();
    for (int d = 1; d < 256; d <<= 1) {
        int t = (tid >= d) ? s[tid - d] : 0;
        __syncthreads();
        s[tid] += t;
        __syncthreads();
    }
    if (i < N_NODES) offs[i] = s[tid] - v;          // exclusive within block
    if (tid == 255) bsum[blockIdx.x] = s[255];
}

// ---------- scan step 2: scan the 196 block sums (single block) ----------
__global__ void k_scan2(int* bsum) {
    __shared__ int s[256];
    int tid = threadIdx.x;
    int v = (tid < NB_SCAN) ? bsum[tid] : 0;
    s[tid] = v;
    __syncthreads();
    for (int d = 1; d < 256; d <<= 1) {
        int t = (tid >= d) ? s[tid - d] : 0;
        __syncthreads();
        s[tid] += t;
        __syncthreads();
    }
    if (tid < NB_SCAN) bsum[tid] = s[tid] - v;      // exclusive
}

// ---------- scan step 3: finalize offs, init cursor, compute dis ----------
__global__ void k_scan3(const int* __restrict__ cnt, int* offs, int* cursor,
                        const int* __restrict__ bsum, float* dis) {
    int i = blockIdx.x * blockDim.x + threadIdx.x;
    if (i < N_NODES) {
        int o = offs[i] + bsum[i >> 8];
        offs[i] = o;
        cursor[i] = o;
        dis[i] = 1.0f / sqrtf((float)(cnt[i] + 1));  // +1 self-loop
    }
}

// ---------- scatter edges into CSR buckets (cursor ends at row end) ----------
__global__ void k_scatter(const int* __restrict__ ei, int* cursor, int* srcidx) {
    int e = blockIdx.x * blockDim.x + threadIdx.x;
    if (e < N_EDGES) {
        int s = ei[e];
        int d = ei[N_EDGES + e];
        int pos = atomicAdd(&cursor[d], 1);
        srcidx[pos] = s;
    }
}

// ---------- hs = (x @ W1) * dis ----------
__global__ void k_gemm_in(const float* __restrict__ x, const float* __restrict__ W1,
                          const float* __restrict__ dis, float* __restrict__ hs) {
    __shared__ float sW[IN_DIM * N_HID];
    int t = threadIdx.x;
    for (int i = t; i < IN_DIM * N_HID; i += blockDim.x) sW[i] = W1[i];
    __syncthreads();
    int node = blockIdx.x * 4 + t / N_HID;
    int j = t % N_HID;
    if (node < N_NODES) {
        float acc = 0.f;
#pragma unroll
        for (int k = 0; k < IN_DIM; ++k) acc += x[node * IN_DIM + k] * sW[k * N_HID + j];
        hs[node * N_HID + j] = acc * dis[node];
    }
}

// ---------- hs2 = (act @ W2) * dis ----------
__global__ void k_gemm_hid(const float* __restrict__ act, const float* __restrict__ W2,
                           const float* __restrict__ dis, float* __restrict__ out) {
    __shared__ float sW[N_HID * N_HID];
    __shared__ float sA[4][N_HID];
    int t = threadIdx.x;  // 256
    for (int i = t; i < N_HID * N_HID; i += 256) sW[i] = W2[i];
    int nl = t / N_HID, j = t % N_HID;   // wave nl owns node nl -> sA broadcast reads
    int node = blockIdx.x * 4 + nl;
    if (node < N_NODES) sA[nl][j] = act[node * N_HID + j];
    __syncthreads();
    if (node < N_NODES) {
        float acc = 0.f;
#pragma unroll
        for (int k = 0; k < N_HID; ++k) acc += sA[nl][k] * sW[k * N_HID + j];
        out[node * N_HID + j] = acc * dis[node];
    }
}

// ---------- aggregate: one wave per node; fused self-loop+norm+bias+ELU ----------
__global__ void k_agg(const float* __restrict__ hs, const int* __restrict__ offs,
                      const int* __restrict__ endp, const int* __restrict__ srcidx,
                      const float* __restrict__ dis, const float* __restrict__ b,
                      float* __restrict__ out) {
    int wid = (blockIdx.x * blockDim.x + threadIdx.x) >> 6;  // node
    int j = threadIdx.x & 63;
    if (wid >= N_NODES) return;
    int start = offs[wid], end = endp[wid];
    float acc = hs[(size_t)wid * N_HID + j];   // self-loop term (hs = h*dis)
    for (int base = start; base < end; base += 64) {
        int n = end - base; if (n > 64) n = 64;
        int myidx = (base + j < end) ? srcidx[base + j] : 0;
        for (int t = 0; t < n; ++t) {
            int s = __shfl(myidx, t);
            acc += hs[(size_t)s * N_HID + j];
        }
    }
    float v = acc * dis[wid] + b[j];
    out[(size_t)wid * N_HID + j] = v > 0.f ? v : expm1f(v);
}

// ---------- graph boundaries (batch is sorted) ----------
__global__ void k_gbounds(const int* __restrict__ batch, int* gstart, int* gcnt) {
    int i = blockIdx.x * blockDim.x + threadIdx.x;
    if (i < N_NODES) {
        int g = batch[i];
        atomicMin(&gstart[g], i);
        atomicAdd(&gcnt[g], 1);
    }
}

// ---------- pool (mean) + head: one wave per graph ----------
__global__ void k_pool_final(const float* __restrict__ h, const int* __restrict__ gstart,
                             const int* __restrict__ gcnt, const float* __restrict__ W3,
                             const float* __restrict__ b3, float* __restrict__ out) {
    int g = blockIdx.x;
    int j = threadIdx.x;  // 64 = one wave
    int cnt = gcnt[g];
    int s = gstart[g];
    float acc = 0.f;
    for (int k = 0; k < cnt; ++k) acc += h[(size_t)(s + k) * N_HID + j];
    float pooled = acc / (float)(cnt > 0 ? cnt : 1);
    float p = pooled * W3[j];
#pragma unroll
    for (int off = 32; off; off >>= 1) p += __shfl_down(p, off);
    if (j == 0) out[g] = p + b3[0];
}

extern "C" void kernel_launch(void* const* d_in, const int* in_sizes, int n_in,
                              void* d_out, int out_size, void* d_ws, size_t ws_size,
                              hipStream_t stream) {
    const float* x   = (const float*)d_in[0];
    const int*   ei  = (const int*)d_in[1];   // [2, E]: row0=src, row1=dst
    const int*   bat = (const int*)d_in[2];
    const float* W1  = (const float*)d_in[3];
    const float* b1  = (const float*)d_in[4];
    const float* W2  = (const float*)d_in[5];
    const float* b2  = (const float*)d_in[6];
    const float* W3  = (const float*)d_in[7];
    const float* b3  = (const float*)d_in[8];
    float* out = (float*)d_out;

    // ---- workspace carve-up ----
    char* w = (char*)d_ws;
    int*   cnt    = (int*)w;            w += NPAD * 4;
    int*   offs   = (int*)w;            w += NPAD * 4;
    int*   cursor = (int*)w;            w += NPAD * 4;
    int*   srcidx = (int*)w;            w += (size_t)N_EDGES * 4;
    int*   bsum   = (int*)w;            w += 256 * 4;
    int*   gstart = (int*)w;            w += 512 * 4;
    int*   gcnt   = (int*)w;            w += 512 * 4;
    float* dis    = (float*)w;          w += NPAD * 4;
    float* bufA   = (float*)w;          w += (size_t)N_NODES * N_HID * 4;
    float* bufB   = (float*)w;          w += (size_t)N_NODES * N_HID * 4;

    const int B = 256;
    const int gN  = (N_NODES + B - 1) / B;
    const int gE  = (N_EDGES + B - 1) / B;
    const int gW  = (N_NODES * 64 + B - 1) / B;   // one wave per node

    // ---- init ----
    hipMemsetAsync(cnt, 0, NPAD * 4, stream);
    hipMemsetAsync(gcnt, 0, 512 * 4, stream);
    hipMemsetAsync(gstart, 0x7f, 512 * 4, stream);

    // ---- CSR build (shared by both layers) ----
    k_hist<<<gE, B, 0, stream>>>(ei, cnt);
    k_scan1<<<NB_SCAN, 256, 0, stream>>>(cnt, offs, bsum);
    k_scan2<<<1, 256, 0, stream>>>(bsum);
    k_scan3<<<gN, B, 0, stream>>>(cnt, offs, cursor, bsum, dis);
    k_scatter<<<gE, B, 0, stream>>>(ei, cursor, srcidx);  // cursor -> row ends
    k_gbounds<<<gN, B, 0, stream>>>(bat, gstart, gcnt);

    // ---- layer 1 ----
    k_gemm_in<<<(N_NODES + 3) / 4, B, 0, stream>>>(x, W1, dis, bufA);
    k_agg<<<gW, B, 0, stream>>>(bufA, offs, cursor, srcidx, dis, b1, bufB);

    // ---- layer 2 ----
    k_gemm_hid<<<(N_NODES + 3) / 4, B, 0, stream>>>(bufB, W2, dis, bufA);
    k_agg<<<gW, B, 0, stream>>>(bufA, offs, cursor, srcidx, dis, b2, bufB);

    // ---- pool + head ----
    k_pool_final<<<N_GRAPHS, 64, 0, stream>>>(bufB, gstart, gcnt, W3, b3, out);
}

// Round 3
// 262.005 us; speedup vs baseline: 2.5071x; 1.4198x over previous
//
#include <hip/hip_runtime.h>
#include <math.h>

#define N_NODES 50000
#define N_EDGES 1000000
#define N_HID 64
#define N_GRAPHS 500
#define IN_DIM 4
#define NPAD 50048

#define BK_SHIFT 7
#define BK_NODES 128                      // nodes per bucket
#define NBUCK 391                         // ceil(50000/128)
#define BCAP 3072                         // mean 2560 + 10 sigma
#define EPT 16                            // edges per thread in k_bin
#define EPW (EPT * 256)                   // 4096 edges per WG
#define NWG_BIN ((N_EDGES + EPW - 1) / EPW)

// ---------- pass A: bin (src,dst) pairs by dst bucket ----------
__global__ void k_bin(const int* __restrict__ ei, int* bcur, int2* __restrict__ P) {
    __shared__ int hist[NBUCK];
    __shared__ int base[NBUCK];
    int t = threadIdx.x;
    int wg0 = blockIdx.x * EPW;
    for (int b = t; b < NBUCK; b += 256) hist[b] = 0;
    __syncthreads();

    int rs[EPT], rd[EPT];
#pragma unroll
    for (int i = 0; i < EPT; ++i) {
        int e = wg0 + i * 256 + t;
        if (e < N_EDGES) {
            rs[i] = ei[e];
            rd[i] = ei[N_EDGES + e];
            atomicAdd(&hist[rd[i] >> BK_SHIFT], 1);
        } else {
            rd[i] = -1;
        }
    }
    __syncthreads();
    for (int b = t; b < NBUCK; b += 256) {
        int h = hist[b];
        base[b] = h ? atomicAdd(&bcur[b], h) : 0;
    }
    __syncthreads();
    for (int b = t; b < NBUCK; b += 256) hist[b] = 0;
    __syncthreads();
#pragma unroll
    for (int i = 0; i < EPT; ++i) {
        if (rd[i] >= 0) {
            int bk = rd[i] >> BK_SHIFT;
            int loc = base[bk] + atomicAdd(&hist[bk], 1);
            if (loc > BCAP - 1) loc = BCAP - 1;   // overflow guard (never expected)
            P[(size_t)bk * BCAP + loc] = make_int2(rs[i], rd[i]);
        }
    }
}

// ---------- pass B: per-bucket counting sort -> CSR rows + dis ----------
__global__ void k_build(const int* __restrict__ bcur, const int2* __restrict__ P,
                        int* __restrict__ srcidx, int* __restrict__ offs,
                        int* __restrict__ endp, float* __restrict__ dis) {
    __shared__ int2 sp[BCAP];
    __shared__ int scnt[BK_NODES];
    __shared__ int sscan[BK_NODES];
    __shared__ int scur[BK_NODES];
    int b = blockIdx.x;
    int t = threadIdx.x;
    int n = bcur[b];
    if (n > BCAP) n = BCAP;
    if (t < BK_NODES) scnt[t] = 0;
    __syncthreads();
    for (int i = t; i < n; i += 256) {
        int2 pr = P[(size_t)b * BCAP + i];
        sp[i] = pr;
        atomicAdd(&scnt[pr.y & (BK_NODES - 1)], 1);
    }
    __syncthreads();
    if (t < BK_NODES) sscan[t] = scnt[t];
    __syncthreads();
    for (int d = 1; d < BK_NODES; d <<= 1) {
        int v = 0;
        if (t < BK_NODES && t >= d) v = sscan[t - d];
        __syncthreads();
        if (t < BK_NODES) sscan[t] += v;
        __syncthreads();
    }
    if (t < BK_NODES) {
        int excl = sscan[t] - scnt[t];
        scur[t] = excl;
        int node = b * BK_NODES + t;
        if (node < N_NODES) {
            int o = b * BCAP + excl;
            offs[node] = o;
            endp[node] = o + scnt[t];
            dis[node] = 1.0f / sqrtf((float)(scnt[t] + 1));
        }
    }
    __syncthreads();
    for (int i = t; i < n; i += 256) {
        int2 pr = sp[i];
        int ln = pr.y & (BK_NODES - 1);
        int pos = b * BCAP + atomicAdd(&scur[ln], 1);
        srcidx[pos] = pr.x;
    }
}

// ---------- hs = (x @ W1) * dis ----------
__global__ void k_gemm_in(const float* __restrict__ x, const float* __restrict__ W1,
                          const float* __restrict__ dis, float* __restrict__ hs) {
    __shared__ float sW[IN_DIM * N_HID];
    int t = threadIdx.x;
    for (int i = t; i < IN_DIM * N_HID; i += blockDim.x) sW[i] = W1[i];
    __syncthreads();
    int node = blockIdx.x * 4 + t / N_HID;
    int j = t % N_HID;
    if (node < N_NODES) {
        float acc = 0.f;
#pragma unroll
        for (int k = 0; k < IN_DIM; ++k) acc += x[node * IN_DIM + k] * sW[k * N_HID + j];
        hs[node * N_HID + j] = acc * dis[node];
    }
}

// ---------- hs2 = (act @ W2) * dis ----------
__global__ void k_gemm_hid(const float* __restrict__ act, const float* __restrict__ W2,
                           const float* __restrict__ dis, float* __restrict__ out) {
    __shared__ float sW[N_HID * N_HID];
    __shared__ float sA[4][N_HID];
    int t = threadIdx.x;  // 256
    for (int i = t; i < N_HID * N_HID; i += 256) sW[i] = W2[i];
    int nl = t / N_HID, j = t % N_HID;
    int node = blockIdx.x * 4 + nl;
    if (node < N_NODES) sA[nl][j] = act[node * N_HID + j];
    __syncthreads();
    if (node < N_NODES) {
        float acc = 0.f;
#pragma unroll
        for (int k = 0; k < N_HID; ++k) acc += sA[nl][k] * sW[k * N_HID + j];
        out[node * N_HID + j] = acc * dis[node];
    }
}

// ---------- aggregate: one wave per node; fused self-loop+norm+bias+ELU ----------
__global__ void k_agg(const float* __restrict__ hs, const int* __restrict__ offs,
                      const int* __restrict__ endp, const int* __restrict__ srcidx,
                      const float* __restrict__ dis, const float* __restrict__ b,
                      float* __restrict__ out) {
    int wid = (blockIdx.x * blockDim.x + threadIdx.x) >> 6;
    int j = threadIdx.x & 63;
    if (wid >= N_NODES) return;
    int start = offs[wid], end = endp[wid];
    float acc = hs[(size_t)wid * N_HID + j];   // self-loop (hs = h*dis)
    for (int base = start; base < end; base += 64) {
        int n = end - base; if (n > 64) n = 64;
        int myidx = (base + j < end) ? srcidx[base + j] : 0;
        for (int t = 0; t < n; ++t) {
            int s = __shfl(myidx, t);
            acc += hs[(size_t)s * N_HID + j];
        }
    }
    float v = acc * dis[wid] + b[j];
    out[(size_t)wid * N_HID + j] = v > 0.f ? v : expm1f(v);
}

// ---------- graph boundaries (batch sorted) ----------
__global__ void k_gbounds(const int* __restrict__ batch, int* gstart, int* gcnt) {
    int i = blockIdx.x * blockDim.x + threadIdx.x;
    if (i < N_NODES) {
        int g = batch[i];
        atomicMin(&gstart[g], i);
        atomicAdd(&gcnt[g], 1);
    }
}

// ---------- pool (mean) + head: one 4-wave block per graph ----------
__global__ void k_pool_final(const float* __restrict__ h, const int* __restrict__ gstart,
                             const int* __restrict__ gcnt, const float* __restrict__ W3,
                             const float* __restrict__ b3, float* __restrict__ out) {
    __shared__ float part[4][N_HID];
    int g = blockIdx.x;
    int t = threadIdx.x;
    int w = t >> 6, j = t & 63;
    int cnt = gcnt[g];
    int s = gstart[g];
    float acc = 0.f;
    for (int k = w; k < cnt; k += 4) acc += h[(size_t)(s + k) * N_HID + j];
    part[w][j] = acc;
    __syncthreads();
    if (w == 0) {
        float v = part[0][j] + part[1][j] + part[2][j] + part[3][j];
        v /= (float)(cnt > 0 ? cnt : 1);
        float p = v * W3[j];
#pragma unroll
        for (int off = 32; off; off >>= 1) p += __shfl_down(p, off);
        if (j == 0) out[g] = p + b3[0];
    }
}

extern "C" void kernel_launch(void* const* d_in, const int* in_sizes, int n_in,
                              void* d_out, int out_size, void* d_ws, size_t ws_size,
                              hipStream_t stream) {
    const float* x   = (const float*)d_in[0];
    const int*   ei  = (const int*)d_in[1];
    const int*   bat = (const int*)d_in[2];
    const float* W1  = (const float*)d_in[3];
    const float* b1  = (const float*)d_in[4];
    const float* W2  = (const float*)d_in[5];
    const float* b2  = (const float*)d_in[6];
    const float* W3  = (const float*)d_in[7];
    const float* b3  = (const float*)d_in[8];
    float* out = (float*)d_out;

    // ---- workspace ----
    char* w = (char*)d_ws;
    int*   bcur   = (int*)w;   w += 512 * 4;
    int*   offs   = (int*)w;   w += NPAD * 4;
    int*   endp   = (int*)w;   w += NPAD * 4;
    float* dis    = (float*)w; w += NPAD * 4;
    int*   gstart = (int*)w;   w += 512 * 4;
    int*   gcnt   = (int*)w;   w += 512 * 4;
    int*   srcidx = (int*)w;   w += (size_t)NBUCK * BCAP * 4;   // 4.8 MB
    float* bufA   = (float*)w; w += (size_t)N_NODES * N_HID * 4; // 12.8 MB
    float* bufB   = (float*)w; w += (size_t)N_NODES * N_HID * 4; // 12.8 MB
    int2*  P      = (int2*)bufB;  // pairs alias bufB (consumed before bufB written)

    const int B = 256;
    const int gN = (N_NODES + B - 1) / B;
    const int gW = (N_NODES * 64 + B - 1) / B;

    hipMemsetAsync(bcur, 0, 512 * 4, stream);
    hipMemsetAsync(gcnt, 0, 512 * 4, stream);
    hipMemsetAsync(gstart, 0x7f, 512 * 4, stream);

    k_bin<<<NWG_BIN, B, 0, stream>>>(ei, bcur, P);
    k_build<<<NBUCK, B, 0, stream>>>(bcur, P, srcidx, offs, endp, dis);
    k_gbounds<<<gN, B, 0, stream>>>(bat, gstart, gcnt);

    k_gemm_in<<<(N_NODES + 3) / 4, B, 0, stream>>>(x, W1, dis, bufA);
    k_agg<<<gW, B, 0, stream>>>(bufA, offs, endp, srcidx, dis, b1, bufB);

    k_gemm_hid<<<(N_NODES + 3) / 4, B, 0, stream>>>(bufB, W2, dis, bufA);
    k_agg<<<gW, B, 0, stream>>>(bufA, offs, endp, srcidx, dis, b2, bufB);

    k_pool_final<<<N_GRAPHS, B, 0, stream>>>(bufB, gstart, gcnt, W3, b3, out);
}

// Round 4
// 201.332 us; speedup vs baseline: 3.2626x; 1.3014x over previous
//
#include <hip/hip_runtime.h>
#include <math.h>

#define N_NODES 50000
#define N_EDGES 1000000
#define N_HID 64
#define N_GRAPHS 500
#define IN_DIM 4
#define NPAD 50048

#define BK_SHIFT 7
#define BK_NODES 128                      // nodes per bucket
#define NBUCK 391                         // ceil(50000/128)
#define BCAP 3072                         // mean 2560 + 10 sigma
#define EPT 16                            // edges per thread in k_bin
#define EPW (EPT * 256)                   // 4096 edges per WG
#define NWG_BIN ((N_EDGES + EPW - 1) / EPW)

// ---------- init (replaces 3 memsets) ----------
__global__ void k_init(int* bcur, int* gstart, int* gcnt) {
    int i = threadIdx.x;   // 512
    if (i < 512) { bcur[i] = 0; gcnt[i] = 0; gstart[i] = N_NODES; }
}

// ---------- pass A: bin packed (src<<7|dstlocal) by dst bucket ----------
__global__ void k_bin(const int* __restrict__ ei, int* bcur, int* __restrict__ P) {
    __shared__ int hist[NBUCK];
    __shared__ int base[NBUCK];
    int t = threadIdx.x;
    int wg0 = blockIdx.x * EPW;
    for (int b = t; b < NBUCK; b += 256) hist[b] = 0;
    __syncthreads();

    int rs[EPT], rd[EPT];
#pragma unroll
    for (int i = 0; i < EPT; ++i) {
        int e = wg0 + i * 256 + t;
        if (e < N_EDGES) {
            rs[i] = ei[e];
            rd[i] = ei[N_EDGES + e];
            atomicAdd(&hist[rd[i] >> BK_SHIFT], 1);
        } else {
            rd[i] = -1;
        }
    }
    __syncthreads();
    for (int b = t; b < NBUCK; b += 256) {
        int h = hist[b];
        base[b] = h ? atomicAdd(&bcur[b], h) : 0;
    }
    __syncthreads();
    for (int b = t; b < NBUCK; b += 256) hist[b] = 0;
    __syncthreads();
#pragma unroll
    for (int i = 0; i < EPT; ++i) {
        if (rd[i] >= 0) {
            int bk = rd[i] >> BK_SHIFT;
            int loc = base[bk] + atomicAdd(&hist[bk], 1);
            if (loc > BCAP - 1) loc = BCAP - 1;   // overflow guard (never expected)
            P[(size_t)bk * BCAP + loc] = (rs[i] << BK_SHIFT) | (rd[i] & (BK_NODES - 1));
        }
    }
}

// ---------- pass B: per-bucket counting sort -> CSR rows + dis ----------
__global__ void k_build(const int* __restrict__ bcur, const int* __restrict__ P,
                        int* __restrict__ srcidx, int* __restrict__ offs,
                        int* __restrict__ endp, float* __restrict__ dis) {
    __shared__ int sp[BCAP];
    __shared__ int scnt[BK_NODES];
    __shared__ int sscan[BK_NODES];
    __shared__ int scur[BK_NODES];
    int b = blockIdx.x;
    int t = threadIdx.x;
    int n = bcur[b];
    if (n > BCAP) n = BCAP;
    if (t < BK_NODES) scnt[t] = 0;
    __syncthreads();
    for (int i = t; i < n; i += 256) {
        int v = P[(size_t)b * BCAP + i];
        sp[i] = v;
        atomicAdd(&scnt[v & (BK_NODES - 1)], 1);
    }
    __syncthreads();
    if (t < BK_NODES) sscan[t] = scnt[t];
    __syncthreads();
    for (int d = 1; d < BK_NODES; d <<= 1) {
        int v = 0;
        if (t < BK_NODES && t >= d) v = sscan[t - d];
        __syncthreads();
        if (t < BK_NODES) sscan[t] += v;
        __syncthreads();
    }
    if (t < BK_NODES) {
        int excl = sscan[t] - scnt[t];
        scur[t] = excl;
        int node = b * BK_NODES + t;
        if (node < N_NODES) {
            int o = b * BCAP + excl;
            offs[node] = o;
            endp[node] = o + scnt[t];
            dis[node] = 1.0f / sqrtf((float)(scnt[t] + 1));
        }
    }
    __syncthreads();
    for (int i = t; i < n; i += 256) {
        int v = sp[i];
        int ln = v & (BK_NODES - 1);
        int pos = b * BCAP + atomicAdd(&scur[ln], 1);
        srcidx[pos] = v >> BK_SHIFT;
    }
}

// ---------- hs = (x @ W1) * dis ----------
__global__ void k_gemm_in(const float* __restrict__ x, const float* __restrict__ W1,
                          const float* __restrict__ dis, float* __restrict__ hs) {
    __shared__ float sW[IN_DIM * N_HID];
    int t = threadIdx.x;
    for (int i = t; i < IN_DIM * N_HID; i += blockDim.x) sW[i] = W1[i];
    __syncthreads();
    int node = blockIdx.x * 4 + t / N_HID;
    int j = t % N_HID;
    if (node < N_NODES) {
        float4 xv = ((const float4*)x)[node];
        float acc = xv.x * sW[0 * N_HID + j] + xv.y * sW[1 * N_HID + j]
                  + xv.z * sW[2 * N_HID + j] + xv.w * sW[3 * N_HID + j];
        hs[node * N_HID + j] = acc * dis[node];
    }
}

// ---------- hs2 = (act @ W2) * dis ----------
__global__ void k_gemm_hid(const float* __restrict__ act, const float* __restrict__ W2,
                           const float* __restrict__ dis, float* __restrict__ out) {
    __shared__ float sW[N_HID * N_HID];
    __shared__ float sA[4][N_HID];
    int t = threadIdx.x;  // 256
    for (int i = t; i < N_HID * N_HID; i += 256) sW[i] = W2[i];
    int nl = t / N_HID, j = t % N_HID;
    int node = blockIdx.x * 4 + nl;
    if (node < N_NODES) sA[nl][j] = act[node * N_HID + j];
    __syncthreads();
    if (node < N_NODES) {
        const float4* sA4 = (const float4*)&sA[nl][0];
        float acc = 0.f;
#pragma unroll
        for (int k4 = 0; k4 < N_HID / 4; ++k4) {
            float4 a = sA4[k4];
            acc += a.x * sW[(k4 * 4 + 0) * N_HID + j];
            acc += a.y * sW[(k4 * 4 + 1) * N_HID + j];
            acc += a.z * sW[(k4 * 4 + 2) * N_HID + j];
            acc += a.w * sW[(k4 * 4 + 3) * N_HID + j];
        }
        out[node * N_HID + j] = acc * dis[node];
    }
}

// ---------- aggregate: one wave per node, 4 edges in flight (float4 lanes) ----------
__global__ void k_agg(const float* __restrict__ hs, const int* __restrict__ offs,
                      const int* __restrict__ endp, const int* __restrict__ srcidx,
                      const float* __restrict__ dis, const float* __restrict__ b,
                      float* __restrict__ out) {
    int wid = (blockIdx.x * blockDim.x + threadIdx.x) >> 6;
    int lane = threadIdx.x & 63;
    int g = lane >> 4, l = lane & 15;
    if (wid >= N_NODES) return;
    const float4* hs4 = (const float4*)hs;
    int start = offs[wid], end = endp[wid];
    float4 acc = make_float4(0.f, 0.f, 0.f, 0.f);
    if (g == 0) acc = hs4[wid * 16 + l];          // self-loop (hs = h*dis)
    for (int base = start; base < end; base += 64) {
        int nc = end - base; if (nc > 64) nc = 64;
        int myidx = (base + lane < end) ? srcidx[base + lane] : 0;
        for (int q = 0; q < nc; q += 4) {          // wave-uniform loop
            int s = __shfl(myidx, q + g);          // group g takes edge q+g
            if (q + g < nc) {
                float4 v = hs4[s * 16 + l];
                acc.x += v.x; acc.y += v.y; acc.z += v.z; acc.w += v.w;
            }
        }
    }
    // fold the 4 group-partials
    acc.x += __shfl_xor(acc.x, 16); acc.y += __shfl_xor(acc.y, 16);
    acc.z += __shfl_xor(acc.z, 16); acc.w += __shfl_xor(acc.w, 16);
    acc.x += __shfl_xor(acc.x, 32); acc.y += __shfl_xor(acc.y, 32);
    acc.z += __shfl_xor(acc.z, 32); acc.w += __shfl_xor(acc.w, 32);
    float dw = dis[wid];
    float4 bb = ((const float4*)b)[l];
    float4 r;
    r.x = acc.x * dw + bb.x; r.y = acc.y * dw + bb.y;
    r.z = acc.z * dw + bb.z; r.w = acc.w * dw + bb.w;
    r.x = r.x > 0.f ? r.x : expm1f(r.x);
    r.y = r.y > 0.f ? r.y : expm1f(r.y);
    r.z = r.z > 0.f ? r.z : expm1f(r.z);
    r.w = r.w > 0.f ? r.w : expm1f(r.w);
    if (g == 0) ((float4*)out)[wid * 16 + l] = r;
}

// ---------- graph boundaries (batch sorted) ----------
__global__ void k_gbounds(const int* __restrict__ batch, int* gstart, int* gcnt) {
    int i = blockIdx.x * blockDim.x + threadIdx.x;
    if (i < N_NODES) {
        int g = batch[i];
        atomicMin(&gstart[g], i);
        atomicAdd(&gcnt[g], 1);
    }
}

// ---------- pool (mean) + head: one 4-wave block per graph ----------
__global__ void k_pool_final(const float* __restrict__ h, const int* __restrict__ gstart,
                             const int* __restrict__ gcnt, const float* __restrict__ W3,
                             const float* __restrict__ b3, float* __restrict__ out) {
    __shared__ float part[4][N_HID];
    int g = blockIdx.x;
    int t = threadIdx.x;
    int w = t >> 6, j = t & 63;
    int cnt = gcnt[g];
    int s = gstart[g];
    float acc = 0.f;
    for (int k = w; k < cnt; k += 4) acc += h[(size_t)(s + k) * N_HID + j];
    part[w][j] = acc;
    __syncthreads();
    if (w == 0) {
        float v = part[0][j] + part[1][j] + part[2][j] + part[3][j];
        v /= (float)(cnt > 0 ? cnt : 1);
        float p = v * W3[j];
#pragma unroll
        for (int off = 32; off; off >>= 1) p += __shfl_down(p, off);
        if (j == 0) out[g] = p + b3[0];
    }
}

extern "C" void kernel_launch(void* const* d_in, const int* in_sizes, int n_in,
                              void* d_out, int out_size, void* d_ws, size_t ws_size,
                              hipStream_t stream) {
    const float* x   = (const float*)d_in[0];
    const int*   ei  = (const int*)d_in[1];
    const int*   bat = (const int*)d_in[2];
    const float* W1  = (const float*)d_in[3];
    const float* b1  = (const float*)d_in[4];
    const float* W2  = (const float*)d_in[5];
    const float* b2  = (const float*)d_in[6];
    const float* W3  = (const float*)d_in[7];
    const float* b3  = (const float*)d_in[8];
    float* out = (float*)d_out;

    // ---- workspace ----
    char* w = (char*)d_ws;
    int*   bcur   = (int*)w;   w += 512 * 4;
    int*   offs   = (int*)w;   w += NPAD * 4;
    int*   endp   = (int*)w;   w += NPAD * 4;
    float* dis    = (float*)w; w += NPAD * 4;
    int*   gstart = (int*)w;   w += 512 * 4;
    int*   gcnt   = (int*)w;   w += 512 * 4;
    int*   srcidx = (int*)w;   w += (size_t)NBUCK * BCAP * 4;    // 4.8 MB
    float* bufA   = (float*)w; w += (size_t)N_NODES * N_HID * 4; // 12.8 MB
    float* bufB   = (float*)w; w += (size_t)N_NODES * N_HID * 4; // 12.8 MB
    int*   P      = (int*)bufB;  // packed pairs alias bufB (consumed before bufB written)

    const int B = 256;
    const int gN = (N_NODES + B - 1) / B;
    const int gW = (N_NODES * 64 + B - 1) / B;

    k_init<<<1, 512, 0, stream>>>(bcur, gstart, gcnt);
    k_bin<<<NWG_BIN, B, 0, stream>>>(ei, bcur, P);
    k_build<<<NBUCK, B, 0, stream>>>(bcur, P, srcidx, offs, endp, dis);
    k_gbounds<<<gN, B, 0, stream>>>(bat, gstart, gcnt);

    k_gemm_in<<<(N_NODES + 3) / 4, B, 0, stream>>>(x, W1, dis, bufA);
    k_agg<<<gW, B, 0, stream>>>(bufA, offs, endp, srcidx, dis, b1, bufB);

    k_gemm_hid<<<(N_NODES + 3) / 4, B, 0, stream>>>(bufB, W2, dis, bufA);
    k_agg<<<gW, B, 0, stream>>>(bufA, offs, endp, srcidx, dis, b2, bufB);

    k_pool_final<<<N_GRAPHS, B, 0, stream>>>(bufB, gstart, gcnt, W3, b3, out);
}